// Round 1
// baseline (12526.162 us; speedup 1.0000x reference)
//
#include <hip/hip_runtime.h>

#define NB   1024   // batch
#define TT   256    // seq len
#define EE   100    // embed dim
#define HH1  64
#define GG1  256    // 4*H1
#define HH2  32
#define GG2  128    // 4*H2
#define NCLS 4
#define RPB  2      // rows per block
#define NTHR 256

__device__ __forceinline__ float fast_sigmoid(float x) {
  // robust: x->-inf: exp(+inf)=inf -> rcp=0 ; x->+inf: exp(0-)=0 -> 1
  return __builtin_amdgcn_rcpf(1.0f + __expf(-x));
}
__device__ __forceinline__ float fast_tanh(float x) {
  // exact identity tanh(x) = 1 - 2/(1+e^{2x}); robust at +-inf
  return 1.0f - 2.0f * __builtin_amdgcn_rcpf(1.0f + __expf(2.0f * x));
}

__global__ __launch_bounds__(NTHR, 2) void lstm_fused(
    const int* __restrict__ tokens, const float* __restrict__ emb,
    const float* __restrict__ W1, const float* __restrict__ U1, const float* __restrict__ b1,
    const float* __restrict__ W2, const float* __restrict__ U2, const float* __restrict__ b2,
    const float* __restrict__ Wd, const float* __restrict__ bd,
    float* __restrict__ out)
{
  // LDS: layer-2 weights natural layout (stride-1 conflict-free reads), activations, gates, tokens
  __shared__ float sW2[HH1][GG2];            // 32 KB
  __shared__ float sU2[HH2][GG2];            // 16 KB
  __shared__ __align__(16) float sX[2][RPB][EE];   // double-buffered embedding rows
  __shared__ __align__(16) float sH1[RPB][HH1];
  __shared__ __align__(16) float sH2[RPB][HH2];
  __shared__ float sZ1[RPB][GG1];
  __shared__ float sZ2[RPB][GG2];
  __shared__ int   sTok[RPB][TT];

  const int j = threadIdx.x;
  const int row0 = blockIdx.x * RPB;

  // ---- one-time init ----
  float w1c[EE];   // W1 column j in registers
  float u1c[HH1];  // U1 column j in registers
  #pragma unroll
  for (int k = 0; k < EE; ++k)  w1c[k] = W1[k * GG1 + j];
  #pragma unroll
  for (int k = 0; k < HH1; ++k) u1c[k] = U1[k * GG1 + j];
  const float bb1 = b1[j];
  const float bb2 = b2[j & (GG2 - 1)];

  for (int idx = j; idx < HH1 * GG2; idx += NTHR) ((float*)sW2)[idx] = W2[idx];
  for (int idx = j; idx < HH2 * GG2; idx += NTHR) ((float*)sU2)[idx] = U2[idx];
  for (int idx = j; idx < RPB * TT; idx += NTHR) {
    int r = idx >> 8, t = idx & (TT - 1);
    sTok[r][t] = tokens[(size_t)(row0 + r) * TT + t];
  }
  if (j < RPB * HH1) { int r = j >> 6, u = j & 63; sH1[r][u] = 0.0f; }
  if (j < RPB * HH2) { int r = j >> 5, u = j & 31; sH2[r][u] = 0.0f; }
  float c1 = 0.0f;  // cell state, owned by thread j<128 : r=j>>6, u=j&63
  float c2 = 0.0f;  // cell state, owned by thread j<64  : r=j>>5, u=j&31
  __syncthreads();

  // ---- prologue: gather x for t=0 into sX[0] ----
  {
    int lane8 = j & 7, grp = j >> 3;
    int task = grp * 2 + lane8;            // spread loads across all 4 waves
    if (lane8 < 2 && task < RPB * (EE / 4)) {
      int r = task / (EE / 4), q = task % (EE / 4);
      int tok = sTok[r][0];
      ((float4*)&sX[0][r][0])[q] = ((const float4*)(emb + (size_t)tok * EE))[q];
    }
  }
  __syncthreads();

  for (int t = 0; t < TT; ++t) {
    const int cur = t & 1, nxt = cur ^ 1;

    // ---- A: prefetch next step's embedding rows into registers (issue early) ----
    float4 pf; int pfr = -1, pfq = 0;
    if (t + 1 < TT) {
      int lane8 = j & 7, grp = j >> 3;
      int task = grp * 2 + lane8;
      if (lane8 < 2 && task < RPB * (EE / 4)) {
        int r = task / (EE / 4), q = task % (EE / 4);
        int tok = sTok[r][t + 1];
        pf = ((const float4*)(emb + (size_t)tok * EE))[q];
        pfr = r; pfq = q;
      }
    }

    // ---- B: layer-1 gate pre-activations; thread j owns gate column j ----
    float acc[RPB];
    #pragma unroll
    for (int r = 0; r < RPB; ++r) acc[r] = bb1;

    #pragma unroll
    for (int q = 0; q < EE / 4; ++q) {         // x @ W1 (W1 col in regs, x broadcast)
      float4 xv[RPB];
      #pragma unroll
      for (int r = 0; r < RPB; ++r) xv[r] = ((const float4*)&sX[cur][r][0])[q];
      #pragma unroll
      for (int kk = 0; kk < 4; ++kk) {
        float w = w1c[4 * q + kk];
        #pragma unroll
        for (int r = 0; r < RPB; ++r)
          acc[r] = fmaf(((const float*)&xv[r])[kk], w, acc[r]);
      }
    }
    #pragma unroll
    for (int q = 0; q < HH1 / 4; ++q) {        // h1 @ U1
      float4 hv[RPB];
      #pragma unroll
      for (int r = 0; r < RPB; ++r) hv[r] = ((const float4*)&sH1[r][0])[q];
      #pragma unroll
      for (int kk = 0; kk < 4; ++kk) {
        float w = u1c[4 * q + kk];
        #pragma unroll
        for (int r = 0; r < RPB; ++r)
          acc[r] = fmaf(((const float*)&hv[r])[kk], w, acc[r]);
      }
    }
    {
      const int gc = j >> 6;                   // 0:i 1:f 2:g 3:o
      #pragma unroll
      for (int r = 0; r < RPB; ++r) {
        float a = acc[r];
        a = (gc == 2) ? fast_tanh(a) : fast_sigmoid(a);
        sZ1[r][j] = a;
      }
    }
    // write prefetched x (after global loads complete; before the barrier)
    if (pfr >= 0) ((float4*)&sX[nxt][pfr][0])[pfq] = pf;
    __syncthreads();

    // ---- C: layer-1 state update; thread j<128 owns (r=j>>6, u=j&63) ----
    if (j < RPB * HH1) {
      int r = j >> 6, u = j & 63;
      bool m = (sTok[r][t] != 0);
      float iv = sZ1[r][u], fv = sZ1[r][64 + u], gv = sZ1[r][128 + u], ov = sZ1[r][192 + u];
      float cn = fv * c1 + iv * gv;
      float hn = ov * fast_tanh(cn);
      if (m) { c1 = cn; sH1[r][u] = hn; }      // masked step: carry h,c unchanged
    }
    __syncthreads();

    // ---- D: layer-2 gate pre-activations; thread j owns (row=j>>7, col=j&127) ----
    {
      int r = j >> 7, c = j & (GG2 - 1);
      float a = bb2;
      #pragma unroll
      for (int q = 0; q < HH1 / 4; ++q) {      // h1 @ W2 (weights stride-1 in LDS)
        float4 hv = ((const float4*)&sH1[r][0])[q];
        a = fmaf(hv.x, sW2[4 * q + 0][c], a);
        a = fmaf(hv.y, sW2[4 * q + 1][c], a);
        a = fmaf(hv.z, sW2[4 * q + 2][c], a);
        a = fmaf(hv.w, sW2[4 * q + 3][c], a);
      }
      #pragma unroll
      for (int q = 0; q < HH2 / 4; ++q) {      // h2 @ U2
        float4 hv = ((const float4*)&sH2[r][0])[q];
        a = fmaf(hv.x, sU2[4 * q + 0][c], a);
        a = fmaf(hv.y, sU2[4 * q + 1][c], a);
        a = fmaf(hv.z, sU2[4 * q + 2][c], a);
        a = fmaf(hv.w, sU2[4 * q + 3][c], a);
      }
      const int gc = c >> 5;                   // 0:i 1:f 2:g 3:o
      a = (gc == 2) ? fast_tanh(a) : fast_sigmoid(a);
      sZ2[r][c] = a;
    }
    __syncthreads();

    // ---- E: layer-2 state update; thread j<64 owns (r=j>>5, u=j&31) ----
    if (j < RPB * HH2) {
      int r = j >> 5, u = j & 31;
      bool m = (sTok[r][t] != 0);
      float iv = sZ2[r][u], fv = sZ2[r][32 + u], gv = sZ2[r][64 + u], ov = sZ2[r][96 + u];
      float cn = fv * c2 + iv * gv;
      float hn = ov * fast_tanh(cn);
      if (m) { c2 = cn; sH2[r][u] = hn; }
    }
    // no barrier needed here: next iteration's first barrier orders E(t) before D(t+1)
  }
  __syncthreads();

  // ---- epilogue: out = sigmoid(h2 @ Wd + bd) ----
  if (j < RPB * NCLS) {
    int r = j >> 2, o = j & 3;
    float a = bd[o];
    #pragma unroll
    for (int u = 0; u < HH2; ++u) a = fmaf(sH2[r][u], Wd[u * NCLS + o], a);
    out[(size_t)(row0 + r) * NCLS + o] = fast_sigmoid(a);
  }
}

extern "C" void kernel_launch(void* const* d_in, const int* in_sizes, int n_in,
                              void* d_out, int out_size, void* d_ws, size_t ws_size,
                              hipStream_t stream) {
  const int*   tokens = (const int*)d_in[0];
  const float* emb    = (const float*)d_in[1];
  const float* W1     = (const float*)d_in[2];
  const float* U1     = (const float*)d_in[3];
  const float* b1     = (const float*)d_in[4];
  const float* W2     = (const float*)d_in[5];
  const float* U2     = (const float*)d_in[6];
  const float* b2     = (const float*)d_in[7];
  const float* Wd     = (const float*)d_in[8];
  const float* bd     = (const float*)d_in[9];
  float* out = (float*)d_out;

  lstm_fused<<<dim3(NB / RPB), dim3(NTHR), 0, stream>>>(
      tokens, emb, W1, U1, b1, W2, U2, b2, Wd, bd, out);
}

// Round 2
// 626.296 us; speedup vs baseline: 20.0004x; 20.0004x over previous
//
#include <hip/hip_runtime.h>

typedef float f4 __attribute__((ext_vector_type(4)));

#define NB   1024   // batch
#define TT   256    // seq len
#define EE   100    // embed dim
#define GG1  256    // 4*H1
#define GG2  128    // 4*H2
#define RPB  4      // rows per block
#define NTHR 512

__device__ __forceinline__ float fast_sigmoid(float x) {
  return __builtin_amdgcn_rcpf(1.0f + __expf(-x));
}
__device__ __forceinline__ float fast_tanh(float x) {
  return 1.0f - 2.0f * __builtin_amdgcn_rcpf(1.0f + __expf(2.0f * x));
}

__global__ __launch_bounds__(NTHR, 2) void lstm_fused(
    const int* __restrict__ tokens, const float* __restrict__ emb,
    const float* __restrict__ W1, const float* __restrict__ U1, const float* __restrict__ b1,
    const float* __restrict__ W2, const float* __restrict__ U2, const float* __restrict__ b2,
    const float* __restrict__ Wd, const float* __restrict__ bd,
    float* __restrict__ out)
{
  __shared__ f4    sX[2][RPB][EE / 4];   // 25 f4 per row, double-buffered
  __shared__ f4    sHH[RPB][24];         // f4 0..15 = h1 (64), 16..23 = h2 (32)
  __shared__ float sZ1[RPB][GG1];
  __shared__ float sZ2[RPB][GG2];
  __shared__ int   sTok[RPB][TT];

  const int tid  = threadIdx.x;
  const int s    = tid & 1;        // k-half
  const int j    = tid >> 1;       // layer-1 gate column 0..255
  const int c    = j & (GG2 - 1);  // layer-2 gate column 0..127
  const int r2   = tid >> 8;       // layer-2 row-pair 0/1 (rows 2*r2, 2*r2+1)
  const int row0 = blockIdx.x * RPB;

  // ---- weights into registers (k-split across lane pairs) ----
  f4 wA[13];  // W1 half: s=0 -> k in [0,50), s=1 -> k in [50,100)
  #pragma unroll
  for (int qq = 0; qq < 13; ++qq) {
    #pragma unroll
    for (int kk = 0; kk < 4; ++kk) {
      int k = 48 * s + 4 * qq + kk;
      bool own = s ? (k >= 50) : (k < 50);
      wA[qq][kk] = own ? W1[k * GG1 + j] : 0.0f;
    }
  }
  f4 uB[8];   // U1 half: k in [32s, 32s+32)
  #pragma unroll
  for (int qq = 0; qq < 8; ++qq) {
    #pragma unroll
    for (int kk = 0; kk < 4; ++kk) {
      int k = 32 * s + 4 * qq + kk;
      uB[qq][kk] = U1[k * GG1 + j];
    }
  }
  f4 wC[12];  // layer-2 combined [W2;U2] column half: kcomb in [48s, 48s+48)
  #pragma unroll
  for (int qq = 0; qq < 12; ++qq) {
    #pragma unroll
    for (int kk = 0; kk < 4; ++kk) {
      int k = 48 * s + 4 * qq + kk;         // 0..63 -> W2 row k ; 64..95 -> U2 row k-64
      wC[qq][kk] = (k < 64) ? W2[k * GG2 + c] : U2[(k - 64) * GG2 + c];
    }
  }
  const float bb1 = b1[j];
  const float bb2 = b2[c];
  const int   gc1 = j >> 6;   // 0:i 1:f 2:g 3:o   (wave-uniform)
  const int   gc2 = c >> 5;   //                    (wave-uniform)

  // ---- one-time LDS init ----
  #pragma unroll
  for (int it = 0; it < (RPB * TT) / NTHR; ++it) {
    int idx = tid + it * NTHR;
    int r = idx >> 8, t = idx & (TT - 1);
    sTok[r][t] = tokens[(size_t)(row0 + r) * TT + t];
  }
  if (tid < RPB * 24 * 4) ((float*)sHH)[tid] = 0.0f;
  float c1 = 0.0f;   // cell state L1: thread tid<256 owns (r=tid>>6, u=tid&63)
  float c2 = 0.0f;   // cell state L2: thread tid<128 owns (r=tid>>5, u=tid&31)
  __syncthreads();

  // ---- prologue: x(t=0) ----
  if (tid >= 256) {
    int task = tid - 256;
    if (task < RPB * (EE / 4)) {
      int r = task / 25, q = task % 25;
      sX[0][r][q] = ((const f4*)(emb + (size_t)sTok[r][0] * EE))[q];
    }
  }
  __syncthreads();

  for (int t = 0; t < TT; ++t) {
    const int cur = t & 1, nxt = cur ^ 1;

    // ---- A: issue prefetch of x(t+1) (waves 4-7) ----
    f4 pf; int pr = -1, pq = 0;
    if (tid >= 256 && t + 1 < TT) {
      int task = tid - 256;
      if (task < RPB * (EE / 4)) {
        pr = task / 25; pq = task % 25;
        pf = ((const f4*)(emb + (size_t)sTok[pr][t + 1] * EE))[pq];
      }
    }

    // ---- B: layer-1 gate partials (all 512 threads) ----
    float a0 = 0.f, a1 = 0.f, a2 = 0.f, a3 = 0.f;
    #pragma unroll
    for (int qq = 0; qq < 13; ++qq) {            // x @ W1 (half)
      int q = 12 * s + qq;
      f4 x0 = sX[cur][0][q], x1 = sX[cur][1][q], x2 = sX[cur][2][q], x3 = sX[cur][3][q];
      #pragma unroll
      for (int kk = 0; kk < 4; ++kk) {
        float w = wA[qq][kk];
        a0 = fmaf(x0[kk], w, a0); a1 = fmaf(x1[kk], w, a1);
        a2 = fmaf(x2[kk], w, a2); a3 = fmaf(x3[kk], w, a3);
      }
    }
    #pragma unroll
    for (int qq = 0; qq < 8; ++qq) {             // h1 @ U1 (half)
      int q = 8 * s + qq;
      f4 h0 = sHH[0][q], h1 = sHH[1][q], h2 = sHH[2][q], h3 = sHH[3][q];
      #pragma unroll
      for (int kk = 0; kk < 4; ++kk) {
        float w = uB[qq][kk];
        a0 = fmaf(h0[kk], w, a0); a1 = fmaf(h1[kk], w, a1);
        a2 = fmaf(h2[kk], w, a2); a3 = fmaf(h3[kk], w, a3);
      }
    }
    a0 += __shfl_xor(a0, 1); a1 += __shfl_xor(a1, 1);
    a2 += __shfl_xor(a2, 1); a3 += __shfl_xor(a3, 1);
    if (s == 0) {
      float z0 = a0 + bb1, z1 = a1 + bb1, z2 = a2 + bb1, z3 = a3 + bb1;
      if (gc1 == 2) { z0 = fast_tanh(z0); z1 = fast_tanh(z1); z2 = fast_tanh(z2); z3 = fast_tanh(z3); }
      else          { z0 = fast_sigmoid(z0); z1 = fast_sigmoid(z1); z2 = fast_sigmoid(z2); z3 = fast_sigmoid(z3); }
      sZ1[0][j] = z0; sZ1[1][j] = z1; sZ1[2][j] = z2; sZ1[3][j] = z3;
    }
    __syncthreads();                             // bar1: sZ1 ready

    // ---- C: layer-1 state update (waves 0-3) | prefetch write (waves 4-7) ----
    if (tid < 256) {
      int r = tid >> 6, u = tid & 63;
      bool m = (sTok[r][t] != 0);
      float iv = sZ1[r][u], fv = sZ1[r][64 + u], gv = sZ1[r][128 + u], ov = sZ1[r][192 + u];
      float cn = fv * c1 + iv * gv;
      float hn = ov * fast_tanh(cn);
      if (m) { c1 = cn; ((float*)&sHH[r][0])[u] = hn; }
    } else if (pr >= 0) {
      sX[nxt][pr][pq] = pf;
    }
    __syncthreads();                             // bar2: h1 ready

    // ---- D: layer-2 gate partials (all 512 threads) ----
    float g0 = 0.f, g1 = 0.f;
    #pragma unroll
    for (int qq = 0; qq < 12; ++qq) {
      int q = 12 * s + qq;
      f4 hA = sHH[2 * r2 + 0][q], hB = sHH[2 * r2 + 1][q];
      #pragma unroll
      for (int kk = 0; kk < 4; ++kk) {
        float w = wC[qq][kk];
        g0 = fmaf(hA[kk], w, g0); g1 = fmaf(hB[kk], w, g1);
      }
    }
    g0 += __shfl_xor(g0, 1); g1 += __shfl_xor(g1, 1);
    if (s == 0) {
      float z0 = g0 + bb2, z1 = g1 + bb2;
      if (gc2 == 2) { z0 = fast_tanh(z0); z1 = fast_tanh(z1); }
      else          { z0 = fast_sigmoid(z0); z1 = fast_sigmoid(z1); }
      sZ2[2 * r2 + 0][c] = z0; sZ2[2 * r2 + 1][c] = z1;
    }
    __syncthreads();                             // bar3: sZ2 ready

    // ---- E: layer-2 state update (waves 0-1); hazards covered by bar1/bar2 of t+1 ----
    if (tid < 128) {
      int r = tid >> 5, u = tid & 31;
      bool m = (sTok[r][t] != 0);
      float iv = sZ2[r][u], fv = sZ2[r][32 + u], gv = sZ2[r][64 + u], ov = sZ2[r][96 + u];
      float cn = fv * c2 + iv * gv;
      float hn = ov * fast_tanh(cn);
      if (m) { c2 = cn; ((float*)&sHH[r][0])[64 + u] = hn; }
    }
  }
  __syncthreads();

  // ---- epilogue: out = sigmoid(h2 @ Wd + bd) ----
  if (tid < RPB * 4) {
    int r = tid >> 2, o = tid & 3;
    float a = bd[o];
    #pragma unroll
    for (int u = 0; u < 32; ++u)
      a = fmaf(((float*)&sHH[r][0])[64 + u], Wd[u * 4 + o], a);
    out[(size_t)(row0 + r) * 4 + o] = fast_sigmoid(a);
  }
}

extern "C" void kernel_launch(void* const* d_in, const int* in_sizes, int n_in,
                              void* d_out, int out_size, void* d_ws, size_t ws_size,
                              hipStream_t stream) {
  const int*   tokens = (const int*)d_in[0];
  const float* emb    = (const float*)d_in[1];
  const float* W1     = (const float*)d_in[2];
  const float* U1     = (const float*)d_in[3];
  const float* b1     = (const float*)d_in[4];
  const float* W2     = (const float*)d_in[5];
  const float* U2     = (const float*)d_in[6];
  const float* b2     = (const float*)d_in[7];
  const float* Wd     = (const float*)d_in[8];
  const float* bd     = (const float*)d_in[9];
  float* out = (float*)d_out;

  lstm_fused<<<dim3(NB / RPB), dim3(NTHR), 0, stream>>>(
      tokens, emb, W1, U1, b1, W2, U2, b2, Wd, bd, out);
}